// Round 5
// baseline (1214.446 us; speedup 1.0000x reference)
//
#include <hip/hip_runtime.h>
#include <hip/hip_bf16.h>
#include <math.h>

// ---------------------------------------------------------------------------
// DeepGT round 4:
//  - k_fill: 8 independent atomic+scatter chains per thread (was 1) -> overlap
//    the ~900-cyc atomic round-trips that made it latency-bound (125us).
//  - k_hist: x4 unroll (fire-and-forget atomics).
//  - attn: batch-4 per 16-lane slot (deg16 node done in ONE softmax update
//    per slot; 8 gathers in flight).
// ---------------------------------------------------------------------------

#define HD 128
#define ODIM 40
#define LDSA 136  // padded LDS row stride (bf16 elems)

typedef __attribute__((ext_vector_type(8))) short short8;
typedef __attribute__((ext_vector_type(4))) float f4v;
typedef __attribute__((ext_vector_type(4))) unsigned short us4;
typedef __attribute__((ext_vector_type(8))) unsigned short us8;

static __device__ __forceinline__ float b2f(unsigned short u) {
  return __uint_as_float(((unsigned)u) << 16);
}
static __device__ __forceinline__ unsigned short f2b(float f) {
  __hip_bfloat16 h = __float2bfloat16(f);
  return __builtin_bit_cast(unsigned short, h);
}

// ---------------- CSR build ----------------

__global__ __launch_bounds__(256) void k_zero(int* __restrict__ p, int n) {
  int i = blockIdx.x * 256 + threadIdx.x;
  if (i < n) p[i] = 0;
}

__global__ __launch_bounds__(256) void k_hist(const int* __restrict__ dst, int E, int* __restrict__ deg) {
  int e0 = blockIdx.x * 1024 + threadIdx.x;
#pragma unroll
  for (int i = 0; i < 4; ++i) {
    int e = e0 + i * 256;
    if (e < E) atomicAdd(&deg[dst[e]], 1);
  }
}

__global__ __launch_bounds__(256) void k_scan_a(const int* __restrict__ deg, int N, int NCH,
                                                int* __restrict__ csum) {
  int c = blockIdx.x * 256 + threadIdx.x;
  if (c >= NCH) return;
  int base = c * 256;
  int lim = min(256, N - base);
  int s = 0;
  for (int i = 0; i < lim; ++i) s += deg[base + i];
  csum[c] = s;
}

__global__ __launch_bounds__(512) void k_scan_b(const int* __restrict__ csum, int NCH,
                                                int* __restrict__ coff) {
  __shared__ int buf[512];
  int t = threadIdx.x;
  int v = (t < NCH) ? csum[t] : 0;
  buf[t] = v;
  __syncthreads();
  for (int off = 1; off < 512; off <<= 1) {
    int x = (t >= off) ? buf[t - off] : 0;
    __syncthreads();
    buf[t] += x;
    __syncthreads();
  }
  if (t < NCH) coff[t] = buf[t] - v;
}

__global__ __launch_bounds__(256) void k_scan_c(const int* __restrict__ deg, const int* __restrict__ coff,
                                                int N, int E, int* __restrict__ rowptr,
                                                int* __restrict__ wp) {
  __shared__ int buf[256];
  int c = blockIdx.x, t = threadIdx.x;
  int i = c * 256 + t;
  int v = (i < N) ? deg[i] : 0;
  buf[t] = v;
  __syncthreads();
  for (int off = 1; off < 256; off <<= 1) {
    int x = (t >= off) ? buf[t - off] : 0;
    __syncthreads();
    buf[t] += x;
    __syncthreads();
  }
  if (i < N) {
    int rp = coff[c] + buf[t] - v;
    rowptr[i] = rp;
    wp[i] = rp;
  }
  if (c == 0 && t == 0) rowptr[N] = E;
}

// 8 independent atomic+scatter chains per thread: overlaps atomic round-trips.
__global__ __launch_bounds__(256) void k_fill(const int* __restrict__ src, const int* __restrict__ dst,
                                              int E, int* __restrict__ wp, int* __restrict__ colsrc) {
  int e0 = blockIdx.x * 2048 + threadIdx.x;
  int d[8], sv[8], p[8];
  bool ok[8];
#pragma unroll
  for (int i = 0; i < 8; ++i) {
    int e = e0 + i * 256;
    ok[i] = (e < E);
    if (ok[i]) { d[i] = dst[e]; sv[i] = src[e]; }
  }
#pragma unroll
  for (int i = 0; i < 8; ++i)
    if (ok[i]) p[i] = atomicAdd(&wp[d[i]], 1);
#pragma unroll
  for (int i = 0; i < 8; ++i)
    if (ok[i]) colsrc[p[i]] = sv[i];
}

// ---------------- weight pack: fp32 [k][n] -> bf16 [n][k] ----------------
// Wp (bf16 elems): [0,16384) lin [128n][128k]; [16384,278528) 4 x [512n][128k]
// (n: 0-127 q, 128-255 k, 256-383 v, 384-511 s); [278528,284672) fc [48n][128k]
// (rows 40-47 zero-padded).

#define PACK_FC   278528
#define PACK_TOT  284672

__global__ __launch_bounds__(256) void k_pack(const float* __restrict__ linW,
                                              const float* __restrict__ Wq, const float* __restrict__ Wk,
                                              const float* __restrict__ Wv, const float* __restrict__ Ws,
                                              const float* __restrict__ fcW,
                                              unsigned short* __restrict__ Wp) {
  int idx = blockIdx.x * 256 + threadIdx.x;
  float val;
  if (idx < 16384) {
    int n = idx >> 7, kk = idx & 127;
    val = linW[kk * 128 + n];
  } else if (idx < PACK_FC) {
    int t = idx - 16384;
    int l = t >> 16, r = t & 65535;
    int n = r >> 7, kk = r & 127;
    int which = n >> 7, nn = n & 127;
    const float* W = (which == 0) ? Wq : (which == 1) ? Wk : (which == 2) ? Wv : Ws;
    val = W[(size_t)l * 16384 + kk * 128 + nn];
  } else if (idx < PACK_TOT) {
    int t = idx - PACK_FC;
    int n = t >> 7, kk = t & 127;
    val = (n < ODIM) ? fcW[kk * ODIM + n] : 0.f;
  } else {
    return;
  }
  Wp[idx] = f2b(val);
}

// ---------------- GEMM lin ----------------

__global__ __launch_bounds__(256) void k_gemm_lin(const float* __restrict__ x,
                                                  const unsigned short* __restrict__ wl,
                                                  const float* __restrict__ bias,
                                                  unsigned short* __restrict__ hb, int N) {
  __shared__ unsigned short As[32 * LDSA];
  int t = threadIdx.x;
  int rowbase = blockIdx.x * 32;
#pragma unroll
  for (int i = 0; i < 2; ++i) {
    int c = t + i * 256;
    int r = c >> 4, c8 = c & 15;
    int gr = rowbase + r;
    if (gr >= N) gr = N - 1;
    const float4* xp = (const float4*)(x + (size_t)gr * 128 + c8 * 8);
    float4 u0 = xp[0], u1 = xp[1];
    us8 o;
    o[0] = f2b(u0.x); o[1] = f2b(u0.y); o[2] = f2b(u0.z); o[3] = f2b(u0.w);
    o[4] = f2b(u1.x); o[5] = f2b(u1.y); o[6] = f2b(u1.z); o[7] = f2b(u1.w);
    *(us8*)(As + r * LDSA + c8 * 8) = o;
  }
  __syncthreads();

  int lane = t & 63, w = t >> 6;
  int rh = (w & 1) * 16;
  int ch = (w >> 1) * 64;
  int lm = lane & 15, lq = lane >> 4;

  short8 a[4];
#pragma unroll
  for (int ks = 0; ks < 4; ++ks)
    a[ks] = *(const short8*)(As + (rh + lm) * LDSA + ks * 32 + lq * 8);
  __syncthreads();

  f4v acc[4];
#pragma unroll
  for (int ct = 0; ct < 4; ++ct) acc[ct] = (f4v){0.f, 0.f, 0.f, 0.f};

#pragma unroll
  for (int ct = 0; ct < 4; ++ct) {
    const short8* bp = (const short8*)(wl + ((size_t)(ch + ct * 16 + lm)) * 128 + lq * 8);
    short8 b0 = bp[0], b1 = bp[4], b2 = bp[8], b3 = bp[12];
    acc[ct] = __builtin_amdgcn_mfma_f32_16x16x32_bf16(a[0], b0, acc[ct], 0, 0, 0);
    acc[ct] = __builtin_amdgcn_mfma_f32_16x16x32_bf16(a[1], b1, acc[ct], 0, 0, 0);
    acc[ct] = __builtin_amdgcn_mfma_f32_16x16x32_bf16(a[2], b2, acc[ct], 0, 0, 0);
    acc[ct] = __builtin_amdgcn_mfma_f32_16x16x32_bf16(a[3], b3, acc[ct], 0, 0, 0);
  }

  unsigned short* stage = As;
#pragma unroll
  for (int ct = 0; ct < 4; ++ct) {
    int c = ch + ct * 16 + lm;
    float bv = bias[c];
#pragma unroll
    for (int r = 0; r < 4; ++r)
      stage[(rh + lq * 4 + r) * 128 + c] = f2b(acc[ct][r] + bv);
  }
  __syncthreads();
#pragma unroll
  for (int i = 0; i < 2; ++i) {
    int c = t + i * 256;
    int r = c >> 4, c8 = c & 15;
    int row = rowbase + r;
    if (row < N)
      *(us8*)(hb + (size_t)row * 128 + c8 * 8) = *(const us8*)(stage + r * 128 + c8 * 8);
  }
}

// ---------------- GEMM fused qkvs ----------------

__global__ __launch_bounds__(256, 3) void k_gemm_qkvs(const unsigned short* __restrict__ hb,
                                                      const unsigned short* __restrict__ wl,
                                                      const float* __restrict__ bq, const float* __restrict__ bk,
                                                      const float* __restrict__ bv, const float* __restrict__ bs,
                                                      unsigned short* __restrict__ q, unsigned short* __restrict__ k,
                                                      unsigned short* __restrict__ v, float* __restrict__ s, int N) {
  __shared__ unsigned short As[32 * LDSA];
  int t = threadIdx.x;
  int rowbase = blockIdx.x * 32;
#pragma unroll
  for (int i = 0; i < 2; ++i) {
    int c = t + i * 256;
    int r = c >> 4, c8 = c & 15;
    int gr = rowbase + r;
    if (gr >= N) gr = N - 1;
    *(us8*)(As + r * LDSA + c8 * 8) = *(const us8*)(hb + (size_t)gr * 128 + c8 * 8);
  }
  __syncthreads();

  int lane = t & 63, w = t >> 6;
  int lm = lane & 15, lq = lane >> 4;

  short8 a[2][4];
#pragma unroll
  for (int rt = 0; rt < 2; ++rt)
#pragma unroll
    for (int ks = 0; ks < 4; ++ks)
      a[rt][ks] = *(const short8*)(As + (rt * 16 + lm) * LDSA + ks * 32 + lq * 8);
  __syncthreads();

  f4v acc[2][8];
#pragma unroll
  for (int rt = 0; rt < 2; ++rt)
#pragma unroll
    for (int ct = 0; ct < 8; ++ct) acc[rt][ct] = (f4v){0.f, 0.f, 0.f, 0.f};

  const unsigned short* wb = wl + (size_t)w * 16384;
#pragma unroll
  for (int ct = 0; ct < 8; ++ct) {
    const short8* bp = (const short8*)(wb + (size_t)(ct * 16 + lm) * 128 + lq * 8);
    short8 b0 = bp[0], b1 = bp[4], b2 = bp[8], b3 = bp[12];
#pragma unroll
    for (int rt = 0; rt < 2; ++rt) {
      acc[rt][ct] = __builtin_amdgcn_mfma_f32_16x16x32_bf16(a[rt][0], b0, acc[rt][ct], 0, 0, 0);
      acc[rt][ct] = __builtin_amdgcn_mfma_f32_16x16x32_bf16(a[rt][1], b1, acc[rt][ct], 0, 0, 0);
      acc[rt][ct] = __builtin_amdgcn_mfma_f32_16x16x32_bf16(a[rt][2], b2, acc[rt][ct], 0, 0, 0);
      acc[rt][ct] = __builtin_amdgcn_mfma_f32_16x16x32_bf16(a[rt][3], b3, acc[rt][ct], 0, 0, 0);
    }
  }

  const float* bsel = (w == 0) ? bq : (w == 1) ? bk : (w == 2) ? bv : bs;
  float bias[8];
#pragma unroll
  for (int ct = 0; ct < 8; ++ct) bias[ct] = bsel[ct * 16 + lm];

  if (w == 3) {
#pragma unroll
    for (int rt = 0; rt < 2; ++rt)
#pragma unroll
      for (int ct = 0; ct < 8; ++ct)
#pragma unroll
        for (int r = 0; r < 4; ++r) {
          int row = rowbase + rt * 16 + lq * 4 + r;
          if (row < N) s[(size_t)row * 128 + ct * 16 + lm] = acc[rt][ct][r] + bias[ct];
        }
  }

  unsigned short* stage = As;
  for (int p = 0; p < 3; ++p) {
    if (w == p) {
#pragma unroll
      for (int rt = 0; rt < 2; ++rt)
#pragma unroll
        for (int ct = 0; ct < 8; ++ct)
#pragma unroll
          for (int r = 0; r < 4; ++r)
            stage[(rt * 16 + lq * 4 + r) * 128 + ct * 16 + lm] = f2b(acc[rt][ct][r] + bias[ct]);
    }
    __syncthreads();
    unsigned short* outp = (p == 0) ? q : (p == 1) ? k : v;
#pragma unroll
    for (int i = 0; i < 2; ++i) {
      int c = t + i * 256;
      int r = c >> 4, c8 = c & 15;
      int row = rowbase + r;
      if (row < N)
        *(us8*)(outp + (size_t)row * 128 + c8 * 8) = *(const us8*)(stage + r * 128 + c8 * 8);
    }
    __syncthreads();
  }
}

// ---------------- attention: one wave/node, 4x16-lane slots, batch-4 ----------------

__global__ __launch_bounds__(256) void k_attn4(const unsigned short* __restrict__ q,
                                               const unsigned short* __restrict__ kb,
                                               const unsigned short* __restrict__ vb,
                                               const float* __restrict__ s,
                                               const int* __restrict__ rowptr, const int* __restrict__ colsrc,
                                               unsigned short* __restrict__ hb, int n, int do_elu) {
  int wid = blockIdx.x * 4 + (threadIdx.x >> 6);
  if (wid >= n) return;
  int lane = threadIdx.x & 63;
  int slot = lane >> 4;
  int lm = lane & 15;
  int d0 = lm * 8;
  const float scale = 0.08838834764831844f;  // 1/sqrt(128)

  us8 qu = *(const us8*)(q + (size_t)wid * 128 + d0);
  float qf[8];
#pragma unroll
  for (int i = 0; i < 8; ++i) qf[i] = b2f(qu[i]);

  int e0 = rowptr[wid], e1 = rowptr[wid + 1];
  int deg = e1 - e0;
  int cbase = deg >> 2, rem = deg & 3;
  int lo = e0 + slot * cbase + min(slot, rem);
  int hi = lo + cbase + (slot < rem ? 1 : 0);

  float M = -INFINITY, S = 0.f;
  float acc[8];
#pragma unroll
  for (int i = 0; i < 8; ++i) acc[i] = 0.f;

  int e = lo;
  // batch-4: typical deg-16 node -> one softmax update per slot
  for (; e + 3 < hi; e += 4) {
    int j0 = colsrc[e], j1 = colsrc[e + 1], j2 = colsrc[e + 2], j3 = colsrc[e + 3];
    us8 k0 = *(const us8*)(kb + (size_t)j0 * 128 + d0);
    us8 k1 = *(const us8*)(kb + (size_t)j1 * 128 + d0);
    us8 k2 = *(const us8*)(kb + (size_t)j2 * 128 + d0);
    us8 k3 = *(const us8*)(kb + (size_t)j3 * 128 + d0);
    us8 v0 = *(const us8*)(vb + (size_t)j0 * 128 + d0);
    us8 v1 = *(const us8*)(vb + (size_t)j1 * 128 + d0);
    us8 v2 = *(const us8*)(vb + (size_t)j2 * 128 + d0);
    us8 v3 = *(const us8*)(vb + (size_t)j3 * 128 + d0);
    float p0 = 0.f, p1 = 0.f, p2 = 0.f, p3 = 0.f;
#pragma unroll
    for (int i = 0; i < 8; ++i) {
      p0 = fmaf(qf[i], b2f(k0[i]), p0);
      p1 = fmaf(qf[i], b2f(k1[i]), p1);
      p2 = fmaf(qf[i], b2f(k2[i]), p2);
      p3 = fmaf(qf[i], b2f(k3[i]), p3);
    }
#pragma unroll
    for (int off = 1; off <= 8; off <<= 1) {
      p0 += __shfl_xor(p0, off, 64);
      p1 += __shfl_xor(p1, off, 64);
      p2 += __shfl_xor(p2, off, 64);
      p3 += __shfl_xor(p3, off, 64);
    }
    float l0 = p0 * scale, l1 = p1 * scale, l2 = p2 * scale, l3 = p3 * scale;
    float newM = fmaxf(fmaxf(M, fmaxf(l0, l1)), fmaxf(l2, l3));
    float f = __expf(M - newM);
    float w0 = __expf(l0 - newM), w1 = __expf(l1 - newM);
    float w2 = __expf(l2 - newM), w3 = __expf(l3 - newM);
    S = S * f + (w0 + w1) + (w2 + w3);
#pragma unroll
    for (int i = 0; i < 8; ++i) {
      float t01 = fmaf(w0, b2f(v0[i]), w1 * b2f(v1[i]));
      float t23 = fmaf(w2, b2f(v2[i]), w3 * b2f(v3[i]));
      acc[i] = fmaf(acc[i], f, t01 + t23);
    }
    M = newM;
  }
  // remainder (<=3 edges)
  for (; e < hi; ++e) {
    int j0 = colsrc[e];
    us8 k0 = *(const us8*)(kb + (size_t)j0 * 128 + d0);
    us8 v0 = *(const us8*)(vb + (size_t)j0 * 128 + d0);
    float p0 = 0.f;
#pragma unroll
    for (int i = 0; i < 8; ++i) p0 = fmaf(qf[i], b2f(k0[i]), p0);
#pragma unroll
    for (int off = 1; off <= 8; off <<= 1) p0 += __shfl_xor(p0, off, 64);
    float l0 = p0 * scale;
    float newM = fmaxf(M, l0);
    float f = __expf(M - newM);
    float w0 = __expf(l0 - newM);
    S = S * f + w0;
#pragma unroll
    for (int i = 0; i < 8; ++i) acc[i] = fmaf(acc[i], f, w0 * b2f(v0[i]));
    M = newM;
  }

  // merge 4 slots (xor 16, then xor 32), guarded for empty (-inf) states
#pragma unroll
  for (int off = 16; off <= 32; off <<= 1) {
    float Mo = __shfl_xor(M, off, 64);
    float So = __shfl_xor(S, off, 64);
    float bo[8];
#pragma unroll
    for (int i = 0; i < 8; ++i) bo[i] = __shfl_xor(acc[i], off, 64);
    float newM = fmaxf(M, Mo);
    float fs, fo;
    if (newM == -INFINITY) {
      fs = 0.f; fo = 0.f;
    } else {
      fs = __expf(M - newM);
      fo = __expf(Mo - newM);
    }
    S = S * fs + So * fo;
#pragma unroll
    for (int i = 0; i < 8; ++i) acc[i] = acc[i] * fs + bo[i] * fo;
    M = newM;
  }

  if (slot == 0) {
    float inv = (S > 0.f) ? 1.f / S : 0.f;
    const float4* sp = (const float4*)(s + (size_t)wid * 128 + d0);
    float4 s0 = sp[0], s1 = sp[1];
    float o[8];
    o[0] = acc[0] * inv + s0.x; o[1] = acc[1] * inv + s0.y;
    o[2] = acc[2] * inv + s0.z; o[3] = acc[3] * inv + s0.w;
    o[4] = acc[4] * inv + s1.x; o[5] = acc[5] * inv + s1.y;
    o[6] = acc[6] * inv + s1.z; o[7] = acc[7] * inv + s1.w;
    us8 ov;
#pragma unroll
    for (int i = 0; i < 8; ++i) {
      float x = o[i];
      if (do_elu) x = (x > 0.f) ? x : (__expf(x) - 1.f);
      ov[i] = f2b(x);
    }
    *(us8*)(hb + (size_t)wid * 128 + d0) = ov;
  }
}

// ---------------- MFMA classifier + fused log_softmax ----------------

__global__ __launch_bounds__(256) void k_fc_mfma(const unsigned short* __restrict__ hb,
                                                 const unsigned short* __restrict__ fcp,
                                                 const float* __restrict__ fcb,
                                                 float* __restrict__ out, int N) {
  __shared__ unsigned short As[64 * LDSA];
  int t = threadIdx.x;
  int rowbase = blockIdx.x * 64;
#pragma unroll
  for (int i = 0; i < 4; ++i) {
    int c = t + i * 256;
    int r = c >> 4, c8 = c & 15;
    int gr = rowbase + r;
    if (gr >= N) gr = N - 1;
    us8 val = *(const us8*)(hb + (size_t)gr * 128 + c8 * 8);
    *(us8*)(As + r * LDSA + c8 * 8) = val;
  }
  __syncthreads();

  int lane = t & 63, w = t >> 6;
  int rh = w * 16;
  int lm = lane & 15, lq = lane >> 4;

  short8 a[4];
#pragma unroll
  for (int ks = 0; ks < 4; ++ks)
    a[ks] = *(const short8*)(As + (rh + lm) * LDSA + ks * 32 + lq * 8);

  f4v acc[3];
#pragma unroll
  for (int ct = 0; ct < 3; ++ct) acc[ct] = (f4v){0.f, 0.f, 0.f, 0.f};

#pragma unroll
  for (int ct = 0; ct < 3; ++ct) {
    const short8* bp = (const short8*)(fcp + ((size_t)(ct * 16 + lm)) * 128 + lq * 8);
    short8 b0 = bp[0], b1 = bp[4], b2 = bp[8], b3 = bp[12];
    acc[ct] = __builtin_amdgcn_mfma_f32_16x16x32_bf16(a[0], b0, acc[ct], 0, 0, 0);
    acc[ct] = __builtin_amdgcn_mfma_f32_16x16x32_bf16(a[1], b1, acc[ct], 0, 0, 0);
    acc[ct] = __builtin_amdgcn_mfma_f32_16x16x32_bf16(a[2], b2, acc[ct], 0, 0, 0);
    acc[ct] = __builtin_amdgcn_mfma_f32_16x16x32_bf16(a[3], b3, acc[ct], 0, 0, 0);
  }

  float bias[3];
#pragma unroll
  for (int ct = 0; ct < 3; ++ct) {
    int c = ct * 16 + lm;
    bias[ct] = (c < ODIM) ? fcb[c] : 0.f;
  }

#pragma unroll
  for (int r = 0; r < 4; ++r) {
    float v0 = acc[0][r] + bias[0];
    float v1 = acc[1][r] + bias[1];
    float v2 = (32 + lm < ODIM) ? (acc[2][r] + bias[2]) : -INFINITY;
    float m = fmaxf(fmaxf(v0, v1), v2);
#pragma unroll
    for (int off = 1; off <= 8; off <<= 1) m = fmaxf(m, __shfl_xor(m, off, 64));
    float sum = __expf(v0 - m) + __expf(v1 - m) + ((32 + lm < ODIM) ? __expf(v2 - m) : 0.f);
#pragma unroll
    for (int off = 1; off <= 8; off <<= 1) sum += __shfl_xor(sum, off, 64);
    float lse = m + logf(sum);
    int row = rowbase + rh + lq * 4 + r;
    if (row < N) {
      float* orow = out + (size_t)row * ODIM;
      orow[lm] = v0 - lse;
      orow[16 + lm] = v1 - lse;
      if (32 + lm < ODIM) orow[32 + lm] = v2 - lse;
    }
  }
}

// ---------------- host ----------------

extern "C" void kernel_launch(void* const* d_in, const int* in_sizes, int n_in,
                              void* d_out, int out_size, void* d_ws, size_t ws_size,
                              hipStream_t stream) {
  const float* x    = (const float*)d_in[0];
  const int*   ei   = (const int*)d_in[1];
  const float* linW = (const float*)d_in[2];
  const float* linb = (const float*)d_in[3];
  const float* Wq   = (const float*)d_in[4];
  const float* bq   = (const float*)d_in[5];
  const float* Wk   = (const float*)d_in[6];
  const float* bk   = (const float*)d_in[7];
  const float* Wv   = (const float*)d_in[8];
  const float* bv   = (const float*)d_in[9];
  const float* Wsk  = (const float*)d_in[10];
  const float* bsk  = (const float*)d_in[11];
  const float* fcW  = (const float*)d_in[12];
  const float* fcb  = (const float*)d_in[13];
  float* out = (float*)d_out;

  const int N = in_sizes[0] / HD;
  const int E = in_sizes[1] / 2;
  const int* srcv = ei;
  const int* dstv = ei + E;

  size_t off = 0;
  char* base = (char*)d_ws;
  auto carve = [&](size_t bytes) -> void* {
    void* p = base + off;
    off = (off + bytes + 255) & ~(size_t)255;
    return p;
  };
  unsigned short* Wp = (unsigned short*)carve((size_t)PACK_TOT * 2);
  unsigned short* hb = (unsigned short*)carve((size_t)N * HD * 2);
  unsigned short* qb = (unsigned short*)carve((size_t)N * HD * 2);
  unsigned short* kbuf = (unsigned short*)carve((size_t)N * HD * 2);
  unsigned short* vbuf = (unsigned short*)carve((size_t)N * HD * 2);
  float* sbuf = (float*)carve((size_t)N * HD * 4);
  int* deg    = (int*)carve((size_t)N * 4);
  int* wp     = (int*)carve((size_t)N * 4);
  int* rowptr = (int*)carve((size_t)(N + 1) * 4);
  int* colsrc = (int*)carve((size_t)E * 4);
  int* csum   = (int*)carve(512 * 4);
  int* coff   = (int*)carve(512 * 4);
  (void)ws_size; (void)n_in; (void)out_size;

  const int NCH = (N + 255) / 256;
  dim3 blk(256);
  int nb = (N + 255) / 256;
  int gx = (N + 31) / 32;
  int wb = (N + 3) / 4;

  // CSR by dst
  k_zero<<<nb, blk, 0, stream>>>(deg, N);
  k_hist<<<(E + 1023) / 1024, blk, 0, stream>>>(dstv, E, deg);
  k_scan_a<<<(NCH + 255) / 256, blk, 0, stream>>>(deg, N, NCH, csum);
  k_scan_b<<<1, 512, 0, stream>>>(csum, NCH, coff);
  k_scan_c<<<NCH, blk, 0, stream>>>(deg, coff, N, E, rowptr, wp);
  k_fill<<<(E + 2047) / 2048, blk, 0, stream>>>(srcv, dstv, E, wp, colsrc);

  // weight pack
  k_pack<<<(PACK_TOT + 255) / 256, blk, 0, stream>>>(linW, Wq, Wk, Wv, Wsk, fcW, Wp);

  // input projection
  k_gemm_lin<<<gx, blk, 0, stream>>>(x, Wp, linb, hb, N);

  // layers
  for (int l = 0; l < 4; ++l) {
    const unsigned short* wl = Wp + 16384 + (size_t)l * 65536;
    k_gemm_qkvs<<<gx, blk, 0, stream>>>(hb, wl, bq + l * HD, bk + l * HD, bv + l * HD, bsk + l * HD,
                                        qb, kbuf, vbuf, sbuf, N);
    k_attn4<<<wb, blk, 0, stream>>>(qb, kbuf, vbuf, sbuf, rowptr, colsrc, hb, N, (l < 3) ? 1 : 0);
  }

  // classifier + fused log_softmax
  k_fc_mfma<<<(N + 63) / 64, blk, 0, stream>>>(hb, Wp + PACK_FC, fcb, out, N);
}

// Round 8
// 1095.486 us; speedup vs baseline: 1.1086x; 1.1086x over previous
//
#include <hip/hip_runtime.h>
#include <hip/hip_bf16.h>
#include <math.h>

// ---------------------------------------------------------------------------
// DeepGT round 7: fix R5/R6 permutation bug (absmax 0.25 both rounds, fp8 was
// NOT the cause). The epilogue's store address pi(np)=(np&15)*8+(np>>4) alone
// creates the permuted layout L(p)=(p&7)*16+(p>>3); the weight n-dim pack must
// be IDENTITY (it was wrongly permuted too -> double application -> content
// sigma(L(p)) misaligned with the k-dim pack's assumed L(p)). k-dim pack stays
// kk=L(k_pos). Everything else = R6 (batch-2 4-slot attn, direct epilogues).
// ---------------------------------------------------------------------------

#define HD 128
#define ODIM 40
#define LDSA 136  // padded LDS row stride (bf16 elems)
#define QK_SCALE 0.08838834764831844f

typedef __attribute__((ext_vector_type(8))) short short8;
typedef __attribute__((ext_vector_type(4))) float f4v;
typedef __attribute__((ext_vector_type(4))) unsigned short us4;
typedef __attribute__((ext_vector_type(8))) unsigned short us8;

static __device__ __forceinline__ float b2f(unsigned short u) {
  return __uint_as_float(((unsigned)u) << 16);
}
static __device__ __forceinline__ unsigned short f2b(float f) {
  __hip_bfloat16 h = __float2bfloat16(f);
  return __builtin_bit_cast(unsigned short, h);
}

// ---------------- CSR build ----------------

__global__ __launch_bounds__(256) void k_zero(int* __restrict__ p, int n) {
  int i = blockIdx.x * 256 + threadIdx.x;
  if (i < n) p[i] = 0;
}

__global__ __launch_bounds__(256) void k_hist(const int* __restrict__ dst, int E, int* __restrict__ deg) {
  int e0 = blockIdx.x * 1024 + threadIdx.x;
#pragma unroll
  for (int i = 0; i < 4; ++i) {
    int e = e0 + i * 256;
    if (e < E) atomicAdd(&deg[dst[e]], 1);
  }
}

__global__ __launch_bounds__(256) void k_scan_a(const int* __restrict__ deg, int N, int NCH,
                                                int* __restrict__ csum) {
  int c = blockIdx.x * 256 + threadIdx.x;
  if (c >= NCH) return;
  int base = c * 256;
  int lim = min(256, N - base);
  int s = 0;
  for (int i = 0; i < lim; ++i) s += deg[base + i];
  csum[c] = s;
}

__global__ __launch_bounds__(512) void k_scan_b(const int* __restrict__ csum, int NCH,
                                                int* __restrict__ coff) {
  __shared__ int buf[512];
  int t = threadIdx.x;
  int v = (t < NCH) ? csum[t] : 0;
  buf[t] = v;
  __syncthreads();
  for (int off = 1; off < 512; off <<= 1) {
    int x = (t >= off) ? buf[t - off] : 0;
    __syncthreads();
    buf[t] += x;
    __syncthreads();
  }
  if (t < NCH) coff[t] = buf[t] - v;
}

__global__ __launch_bounds__(256) void k_scan_c(const int* __restrict__ deg, const int* __restrict__ coff,
                                                int N, int E, int* __restrict__ rowptr,
                                                int* __restrict__ wp) {
  __shared__ int buf[256];
  int c = blockIdx.x, t = threadIdx.x;
  int i = c * 256 + t;
  int v = (i < N) ? deg[i] : 0;
  buf[t] = v;
  __syncthreads();
  for (int off = 1; off < 256; off <<= 1) {
    int x = (t >= off) ? buf[t - off] : 0;
    __syncthreads();
    buf[t] += x;
    __syncthreads();
  }
  if (i < N) {
    int rp = coff[c] + buf[t] - v;
    rowptr[i] = rp;
    wp[i] = rp;
  }
  if (c == 0 && t == 0) rowptr[N] = E;
}

// 8 independent atomic+scatter chains per thread (R4 win)
__global__ __launch_bounds__(256) void k_fill(const int* __restrict__ src, const int* __restrict__ dst,
                                              int E, int* __restrict__ wp, int* __restrict__ colsrc) {
  int e0 = blockIdx.x * 2048 + threadIdx.x;
  int d[8], sv[8], p[8];
  bool ok[8];
#pragma unroll
  for (int i = 0; i < 8; ++i) {
    int e = e0 + i * 256;
    ok[i] = (e < E);
    if (ok[i]) { d[i] = dst[e]; sv[i] = src[e]; }
  }
#pragma unroll
  for (int i = 0; i < 8; ++i)
    if (ok[i]) p[i] = atomicAdd(&wp[d[i]], 1);
#pragma unroll
  for (int i = 0; i < 8; ++i)
    if (ok[i]) colsrc[p[i]] = sv[i];
}

// ---------------- weight pack: fp32 [k][n] -> bf16 [n][k_pos] ----------------
// n-dim: IDENTITY (the epilogue's store address realizes the permutation).
// k-dim: position k_pos holds logical kk = L(k_pos) = 16*(k_pos&7)+(k_pos>>3),
// matching h's layout (position p holds logical col L(p)). Applied to layer
// weights' and fc's k-dim; lin's k-dim is standard (x is unpermuted fp32).

#define PACK_FC   278528
#define PACK_TOT  284672

__global__ __launch_bounds__(256) void k_pack(const float* __restrict__ linW,
                                              const float* __restrict__ Wq, const float* __restrict__ Wk,
                                              const float* __restrict__ Wv, const float* __restrict__ Ws,
                                              const float* __restrict__ fcW,
                                              unsigned short* __restrict__ Wp) {
  int idx = blockIdx.x * 256 + threadIdx.x;
  float val;
  if (idx < 16384) {
    int n = idx >> 7, kk = idx & 127;               // n identity, k standard
    val = linW[kk * 128 + n];
  } else if (idx < PACK_FC) {
    int t = idx - 16384;
    int l = t >> 16, r = t & 65535;
    int n_pos = r >> 7, k_pos = r & 127;
    int which = n_pos >> 7;
    int nn = n_pos & 127;                           // n identity
    int kk = 16 * (k_pos & 7) + (k_pos >> 3);       // k = L(k_pos)
    const float* W = (which == 0) ? Wq : (which == 1) ? Wk : (which == 2) ? Wv : Ws;
    val = W[(size_t)l * 16384 + kk * 128 + nn];
  } else if (idx < PACK_TOT) {
    int t = idx - PACK_FC;
    int n = t >> 7, k_pos = t & 127;
    int kk = 16 * (k_pos & 7) + (k_pos >> 3);       // k = L(k_pos); n identity
    val = (n < ODIM) ? fcW[kk * ODIM + n] : 0.f;
  } else {
    return;
  }
  Wp[idx] = f2b(val);
}

// ---------------- GEMM lin: hb[N,128] = bf16( x @ linW + linb ), layout L ----

__global__ __launch_bounds__(256) void k_gemm_lin(const float* __restrict__ x,
                                                  const unsigned short* __restrict__ wl,
                                                  const float* __restrict__ bias,
                                                  unsigned short* __restrict__ hb, int N) {
  __shared__ unsigned short As[32 * LDSA];
  int t = threadIdx.x;
  int rowbase = blockIdx.x * 32;
#pragma unroll
  for (int i = 0; i < 2; ++i) {
    int c = t + i * 256;
    int r = c >> 4, c8 = c & 15;
    int gr = rowbase + r;
    if (gr >= N) gr = N - 1;
    const float4* xp = (const float4*)(x + (size_t)gr * 128 + c8 * 8);
    float4 u0 = xp[0], u1 = xp[1];
    us8 o;
    o[0] = f2b(u0.x); o[1] = f2b(u0.y); o[2] = f2b(u0.z); o[3] = f2b(u0.w);
    o[4] = f2b(u1.x); o[5] = f2b(u1.y); o[6] = f2b(u1.z); o[7] = f2b(u1.w);
    *(us8*)(As + r * LDSA + c8 * 8) = o;
  }
  __syncthreads();

  int lane = t & 63, w = t >> 6;
  int rh = (w & 1) * 16;
  int ch = (w >> 1) * 64;
  int lm = lane & 15, lq = lane >> 4;

  short8 a[4];
#pragma unroll
  for (int ks = 0; ks < 4; ++ks)
    a[ks] = *(const short8*)(As + (rh + lm) * LDSA + ks * 32 + lq * 8);

  f4v acc[4];
#pragma unroll
  for (int ct = 0; ct < 4; ++ct) acc[ct] = (f4v){0.f, 0.f, 0.f, 0.f};

#pragma unroll
  for (int ct = 0; ct < 4; ++ct) {
    const short8* bp = (const short8*)(wl + ((size_t)(ch + ct * 16 + lm)) * 128 + lq * 8);
    short8 b0 = bp[0], b1 = bp[4], b2 = bp[8], b3 = bp[12];
    acc[ct] = __builtin_amdgcn_mfma_f32_16x16x32_bf16(a[0], b0, acc[ct], 0, 0, 0);
    acc[ct] = __builtin_amdgcn_mfma_f32_16x16x32_bf16(a[1], b1, acc[ct], 0, 0, 0);
    acc[ct] = __builtin_amdgcn_mfma_f32_16x16x32_bf16(a[2], b2, acc[ct], 0, 0, 0);
    acc[ct] = __builtin_amdgcn_mfma_f32_16x16x32_bf16(a[3], b3, acc[ct], 0, 0, 0);
  }

  float bv[4];
#pragma unroll
  for (int ct = 0; ct < 4; ++ct) bv[ct] = bias[ch + ct * 16 + lm];

  // store B-row np=ch+ct*16+lm at position pi(np)=lm*8+(w>>1)*4+ct
#pragma unroll
  for (int r = 0; r < 4; ++r) {
    int row = rowbase + rh + lq * 4 + r;
    if (row < N) {
      us4 ov;
#pragma unroll
      for (int ct = 0; ct < 4; ++ct) ov[ct] = f2b(acc[ct][r] + bv[ct]);
      *(us4*)(hb + (size_t)row * 128 + lm * 8 + (w >> 1) * 4) = ov;
    }
  }
}

// ---------------- GEMM fused qkvs: wave w computes tensor w (32r x 128c) -------

__global__ __launch_bounds__(256, 3) void k_gemm_qkvs(const unsigned short* __restrict__ hb,
                                                      const unsigned short* __restrict__ wl,
                                                      const float* __restrict__ bq, const float* __restrict__ bk,
                                                      const float* __restrict__ bv, const float* __restrict__ bs,
                                                      unsigned short* __restrict__ q, unsigned short* __restrict__ k,
                                                      unsigned short* __restrict__ v, float* __restrict__ s, int N) {
  __shared__ unsigned short As[32 * LDSA];
  int t = threadIdx.x;
  int rowbase = blockIdx.x * 32;
#pragma unroll
  for (int i = 0; i < 2; ++i) {
    int c = t + i * 256;
    int r = c >> 4, c8 = c & 15;
    int gr = rowbase + r;
    if (gr >= N) gr = N - 1;
    *(us8*)(As + r * LDSA + c8 * 8) = *(const us8*)(hb + (size_t)gr * 128 + c8 * 8);
  }
  __syncthreads();

  int lane = t & 63, w = t >> 6;   // w: 0 q, 1 k, 2 v, 3 s
  int lm = lane & 15, lq = lane >> 4;

  short8 a[2][4];
#pragma unroll
  for (int rt = 0; rt < 2; ++rt)
#pragma unroll
    for (int ks = 0; ks < 4; ++ks)
      a[rt][ks] = *(const short8*)(As + (rt * 16 + lm) * LDSA + ks * 32 + lq * 8);

  f4v acc[2][8];
#pragma unroll
  for (int rt = 0; rt < 2; ++rt)
#pragma unroll
    for (int ct = 0; ct < 8; ++ct) acc[rt][ct] = (f4v){0.f, 0.f, 0.f, 0.f};

  const unsigned short* wb = wl + (size_t)w * 16384;
#pragma unroll
  for (int ct = 0; ct < 8; ++ct) {
    const short8* bp = (const short8*)(wb + (size_t)(ct * 16 + lm) * 128 + lq * 8);
    short8 b0 = bp[0], b1 = bp[4], b2 = bp[8], b3 = bp[12];
#pragma unroll
    for (int rt = 0; rt < 2; ++rt) {
      acc[rt][ct] = __builtin_amdgcn_mfma_f32_16x16x32_bf16(a[rt][0], b0, acc[rt][ct], 0, 0, 0);
      acc[rt][ct] = __builtin_amdgcn_mfma_f32_16x16x32_bf16(a[rt][1], b1, acc[rt][ct], 0, 0, 0);
      acc[rt][ct] = __builtin_amdgcn_mfma_f32_16x16x32_bf16(a[rt][2], b2, acc[rt][ct], 0, 0, 0);
      acc[rt][ct] = __builtin_amdgcn_mfma_f32_16x16x32_bf16(a[rt][3], b3, acc[rt][ct], 0, 0, 0);
    }
  }

  const float* bsel = (w == 0) ? bq : (w == 1) ? bk : (w == 2) ? bv : bs;
  float bias[8];
#pragma unroll
  for (int ct = 0; ct < 8; ++ct) bias[ct] = bsel[ct * 16 + lm];

#pragma unroll
  for (int rt = 0; rt < 2; ++rt) {
#pragma unroll
    for (int r = 0; r < 4; ++r) {
      int row = rowbase + rt * 16 + lq * 4 + r;
      if (row >= N) continue;
      float vals[8];
#pragma unroll
      for (int ct = 0; ct < 8; ++ct) vals[ct] = acc[rt][ct][r] + bias[ct];
      if (w == 3) {
        *(float4*)(s + (size_t)row * 128 + lm * 8) = make_float4(vals[0], vals[1], vals[2], vals[3]);
        *(float4*)(s + (size_t)row * 128 + lm * 8 + 4) = make_float4(vals[4], vals[5], vals[6], vals[7]);
      } else {
        us8 ov;
#pragma unroll
        for (int ct = 0; ct < 8; ++ct) ov[ct] = f2b(vals[ct]);
        unsigned short* outp = (w == 0) ? q : (w == 1) ? k : v;
        *(us8*)(outp + (size_t)row * 128 + lm * 8) = ov;
      }
    }
  }
}

// ---------------- attention: one wave/node, 4x16-lane slots, batch-2 ----------

__global__ __launch_bounds__(256) void k_attn6(const unsigned short* __restrict__ q,
                                               const unsigned short* __restrict__ kb,
                                               const unsigned short* __restrict__ vb,
                                               const float* __restrict__ s,
                                               const int* __restrict__ rowptr, const int* __restrict__ colsrc,
                                               unsigned short* __restrict__ hb, int n, int do_elu) {
  int wid = blockIdx.x * 4 + (threadIdx.x >> 6);
  if (wid >= n) return;
  int lane = threadIdx.x & 63;
  int slot = lane >> 4;
  int lm = lane & 15;
  int d0 = lm * 8;

  us8 qu = *(const us8*)(q + (size_t)wid * 128 + d0);
  float qf[8];
#pragma unroll
  for (int i = 0; i < 8; ++i) qf[i] = b2f(qu[i]);

  int e0 = rowptr[wid], e1 = rowptr[wid + 1];
  int deg = e1 - e0;
  int cbase = deg >> 2, rem = deg & 3;
  int lo = e0 + slot * cbase + min(slot, rem);
  int hi = lo + cbase + (slot < rem ? 1 : 0);

  float M = -INFINITY, S = 0.f;
  float acc[8];
#pragma unroll
  for (int i = 0; i < 8; ++i) acc[i] = 0.f;

  int e = lo;
  for (; e + 1 < hi; e += 2) {
    int j0 = colsrc[e], j1 = colsrc[e + 1];
    us8 k0 = *(const us8*)(kb + (size_t)j0 * 128 + d0);
    us8 k1 = *(const us8*)(kb + (size_t)j1 * 128 + d0);
    us8 v0 = *(const us8*)(vb + (size_t)j0 * 128 + d0);
    us8 v1 = *(const us8*)(vb + (size_t)j1 * 128 + d0);
    float p0 = 0.f, p1 = 0.f;
#pragma unroll
    for (int i = 0; i < 8; ++i) {
      p0 = fmaf(qf[i], b2f(k0[i]), p0);
      p1 = fmaf(qf[i], b2f(k1[i]), p1);
    }
#pragma unroll
    for (int off = 1; off <= 8; off <<= 1) {
      p0 += __shfl_xor(p0, off, 64);
      p1 += __shfl_xor(p1, off, 64);
    }
    float l0 = p0 * QK_SCALE, l1 = p1 * QK_SCALE;
    float newM = fmaxf(M, fmaxf(l0, l1));
    float f = __expf(M - newM);
    float w0 = __expf(l0 - newM), w1 = __expf(l1 - newM);
    S = S * f + w0 + w1;
#pragma unroll
    for (int i = 0; i < 8; ++i)
      acc[i] = fmaf(acc[i], f, fmaf(w0, b2f(v0[i]), w1 * b2f(v1[i])));
    M = newM;
  }
  if (e < hi) {
    int j0 = colsrc[e];
    us8 k0 = *(const us8*)(kb + (size_t)j0 * 128 + d0);
    us8 v0 = *(const us8*)(vb + (size_t)j0 * 128 + d0);
    float p0 = 0.f;
#pragma unroll
    for (int i = 0; i < 8; ++i) p0 = fmaf(qf[i], b2f(k0[i]), p0);
#pragma unroll
    for (int off = 1; off <= 8; off <<= 1) p0 += __shfl_xor(p0, off, 64);
    float l0 = p0 * QK_SCALE;
    float newM = fmaxf(M, l0);
    float f = __expf(M - newM);
    float w0 = __expf(l0 - newM);
    S = S * f + w0;
#pragma unroll
    for (int i = 0; i < 8; ++i) acc[i] = fmaf(acc[i], f, w0 * b2f(v0[i]));
    M = newM;
  }

  // merge 4 slots (xor 16, then xor 32), guarded for empty (-inf) states
#pragma unroll
  for (int off = 16; off <= 32; off <<= 1) {
    float Mo = __shfl_xor(M, off, 64);
    float So = __shfl_xor(S, off, 64);
    float bo[8];
#pragma unroll
    for (int i = 0; i < 8; ++i) bo[i] = __shfl_xor(acc[i], off, 64);
    float newM = fmaxf(M, Mo);
    float fs, fo;
    if (newM == -INFINITY) {
      fs = 0.f; fo = 0.f;
    } else {
      fs = __expf(M - newM);
      fo = __expf(Mo - newM);
    }
    S = S * fs + So * fo;
#pragma unroll
    for (int i = 0; i < 8; ++i) acc[i] = acc[i] * fs + bo[i] * fo;
    M = newM;
  }

  if (slot == 0) {
    float inv = (S > 0.f) ? 1.f / S : 0.f;
    const float4* sp = (const float4*)(s + (size_t)wid * 128 + d0);
    float4 s0 = sp[0], s1 = sp[1];
    float o[8];
    o[0] = acc[0] * inv + s0.x; o[1] = acc[1] * inv + s0.y;
    o[2] = acc[2] * inv + s0.z; o[3] = acc[3] * inv + s0.w;
    o[4] = acc[4] * inv + s1.x; o[5] = acc[5] * inv + s1.y;
    o[6] = acc[6] * inv + s1.z; o[7] = acc[7] * inv + s1.w;
    us8 ov;
#pragma unroll
    for (int i = 0; i < 8; ++i) {
      float x = o[i];
      if (do_elu) x = (x > 0.f) ? x : (__expf(x) - 1.f);
      ov[i] = f2b(x);
    }
    *(us8*)(hb + (size_t)wid * 128 + d0) = ov;
  }
}

// ---------------- MFMA classifier + fused log_softmax ----------------

__global__ __launch_bounds__(256) void k_fc_mfma(const unsigned short* __restrict__ hb,
                                                 const unsigned short* __restrict__ fcp,
                                                 const float* __restrict__ fcb,
                                                 float* __restrict__ out, int N) {
  __shared__ unsigned short As[64 * LDSA];
  int t = threadIdx.x;
  int rowbase = blockIdx.x * 64;
#pragma unroll
  for (int i = 0; i < 4; ++i) {
    int c = t + i * 256;
    int r = c >> 4, c8 = c & 15;
    int gr = rowbase + r;
    if (gr >= N) gr = N - 1;
    us8 val = *(const us8*)(hb + (size_t)gr * 128 + c8 * 8);
    *(us8*)(As + r * LDSA + c8 * 8) = val;
  }
  __syncthreads();

  int lane = t & 63, w = t >> 6;
  int rh = w * 16;
  int lm = lane & 15, lq = lane >> 4;

  short8 a[4];
#pragma unroll
  for (int ks = 0; ks < 4; ++ks)
    a[ks] = *(const short8*)(As + (rh + lm) * LDSA + ks * 32 + lq * 8);

  f4v acc[3];
#pragma unroll
  for (int ct = 0; ct < 3; ++ct) acc[ct] = (f4v){0.f, 0.f, 0.f, 0.f};

#pragma unroll
  for (int ct = 0; ct < 3; ++ct) {
    const short8* bp = (const short8*)(fcp + ((size_t)(ct * 16 + lm)) * 128 + lq * 8);
    short8 b0 = bp[0], b1 = bp[4], b2 = bp[8], b3 = bp[12];
    acc[ct] = __builtin_amdgcn_mfma_f32_16x16x32_bf16(a[0], b0, acc[ct], 0, 0, 0);
    acc[ct] = __builtin_amdgcn_mfma_f32_16x16x32_bf16(a[1], b1, acc[ct], 0, 0, 0);
    acc[ct] = __builtin_amdgcn_mfma_f32_16x16x32_bf16(a[2], b2, acc[ct], 0, 0, 0);
    acc[ct] = __builtin_amdgcn_mfma_f32_16x16x32_bf16(a[3], b3, acc[ct], 0, 0, 0);
  }

  float bias[3];
#pragma unroll
  for (int ct = 0; ct < 3; ++ct) {
    int c = ct * 16 + lm;
    bias[ct] = (c < ODIM) ? fcb[c] : 0.f;
  }

#pragma unroll
  for (int r = 0; r < 4; ++r) {
    float v0 = acc[0][r] + bias[0];
    float v1 = acc[1][r] + bias[1];
    float v2 = (32 + lm < ODIM) ? (acc[2][r] + bias[2]) : -INFINITY;
    float m = fmaxf(fmaxf(v0, v1), v2);
#pragma unroll
    for (int off = 1; off <= 8; off <<= 1) m = fmaxf(m, __shfl_xor(m, off, 64));
    float sum = __expf(v0 - m) + __expf(v1 - m) + ((32 + lm < ODIM) ? __expf(v2 - m) : 0.f);
#pragma unroll
    for (int off = 1; off <= 8; off <<= 1) sum += __shfl_xor(sum, off, 64);
    float lse = m + logf(sum);
    int row = rowbase + rh + lq * 4 + r;
    if (row < N) {
      float* orow = out + (size_t)row * ODIM;
      orow[lm] = v0 - lse;
      orow[16 + lm] = v1 - lse;
      if (32 + lm < ODIM) orow[32 + lm] = v2 - lse;
    }
  }
}

// ---------------- host ----------------

extern "C" void kernel_launch(void* const* d_in, const int* in_sizes, int n_in,
                              void* d_out, int out_size, void* d_ws, size_t ws_size,
                              hipStream_t stream) {
  const float* x    = (const float*)d_in[0];
  const int*   ei   = (const int*)d_in[1];
  const float* linW = (const float*)d_in[2];
  const float* linb = (const float*)d_in[3];
  const float* Wq   = (const float*)d_in[4];
  const float* bq   = (const float*)d_in[5];
  const float* Wk   = (const float*)d_in[6];
  const float* bk   = (const float*)d_in[7];
  const float* Wv   = (const float*)d_in[8];
  const float* bv   = (const float*)d_in[9];
  const float* Wsk  = (const float*)d_in[10];
  const float* bsk  = (const float*)d_in[11];
  const float* fcW  = (const float*)d_in[12];
  const float* fcb  = (const float*)d_in[13];
  float* out = (float*)d_out;

  const int N = in_sizes[0] / HD;
  const int E = in_sizes[1] / 2;
  const int* srcv = ei;
  const int* dstv = ei + E;

  size_t off = 0;
  char* base = (char*)d_ws;
  auto carve = [&](size_t bytes) -> void* {
    void* p = base + off;
    off = (off + bytes + 255) & ~(size_t)255;
    return p;
  };
  unsigned short* Wp = (unsigned short*)carve((size_t)PACK_TOT * 2);
  unsigned short* hb = (unsigned short*)carve((size_t)N * HD * 2);
  unsigned short* qb = (unsigned short*)carve((size_t)N * HD * 2);
  unsigned short* kbuf = (unsigned short*)carve((size_t)N * HD * 2);
  unsigned short* vbuf = (unsigned short*)carve((size_t)N * HD * 2);
  float* sbuf = (float*)carve((size_t)N * HD * 4);
  int* deg    = (int*)carve((size_t)N * 4);
  int* wp     = (int*)carve((size_t)N * 4);
  int* rowptr = (int*)carve((size_t)(N + 1) * 4);
  int* colsrc = (int*)carve((size_t)E * 4);
  int* csum   = (int*)carve(512 * 4);
  int* coff   = (int*)carve(512 * 4);
  (void)ws_size; (void)n_in; (void)out_size;

  const int NCH = (N + 255) / 256;
  dim3 blk(256);
  int nb = (N + 255) / 256;
  int gx = (N + 31) / 32;
  int wb = (N + 3) / 4;

  // CSR by dst
  k_zero<<<nb, blk, 0, stream>>>(deg, N);
  k_hist<<<(E + 1023) / 1024, blk, 0, stream>>>(dstv, E, deg);
  k_scan_a<<<(NCH + 255) / 256, blk, 0, stream>>>(deg, N, NCH, csum);
  k_scan_b<<<1, 512, 0, stream>>>(csum, NCH, coff);
  k_scan_c<<<NCH, blk, 0, stream>>>(deg, coff, N, E, rowptr, wp);
  k_fill<<<(E + 2047) / 2048, blk, 0, stream>>>(srcv, dstv, E, wp, colsrc);

  // weight pack (k-dim permuted to layout L, n-dim identity)
  k_pack<<<(PACK_TOT + 255) / 256, blk, 0, stream>>>(linW, Wq, Wk, Wv, Wsk, fcW, Wp);

  // input projection
  k_gemm_lin<<<gx, blk, 0, stream>>>(x, Wp, linb, hb, N);

  // layers
  for (int l = 0; l < 4; ++l) {
    const unsigned short* wl = Wp + 16384 + (size_t)l * 65536;
    k_gemm_qkvs<<<gx, blk, 0, stream>>>(hb, wl, bq + l * HD, bk + l * HD, bv + l * HD, bsk + l * HD,
                                        qb, kbuf, vbuf, sbuf, N);
    k_attn6<<<wb, blk, 0, stream>>>(qb, kbuf, vbuf, sbuf, rowptr, colsrc, hb, N, (l < 3) ? 1 : 0);
  }

  // classifier + fused log_softmax
  k_fc_mfma<<<(N + 63) / 64, blk, 0, stream>>>(hb, Wp + PACK_FC, fcb, out, N);
}

// Round 9
// 952.264 us; speedup vs baseline: 1.2753x; 1.1504x over previous
//
#include <hip/hip_runtime.h>
#include <hip/hip_bf16.h>
#include <math.h>

// ---------------------------------------------------------------------------
// DeepGT round 8: R7 base (perm bug fixed, absmax 0.0156) +
//  - k as fp8 e4m3 with QK_SCALE folded (R5's fp8 was exonerated: R6 failed
//    identically without it; the 0.25 was the perm bug). Halves k-gather bytes
//    and k's cache footprint.
//  - s as bf16 (h rounds to bf16 anyway): -51 MB of traffic.
//  - CSR: scan_a block-reduce; hist 8 chains.
// ---------------------------------------------------------------------------

#define HD 128
#define ODIM 40
#define LDSA 136  // padded LDS row stride (bf16 elems)
#define QK_SCALE 0.08838834764831844f

typedef __attribute__((ext_vector_type(8))) short short8;
typedef __attribute__((ext_vector_type(4))) float f4v;
typedef __attribute__((ext_vector_type(2))) float f2v;
typedef __attribute__((ext_vector_type(4))) unsigned short us4;
typedef __attribute__((ext_vector_type(8))) unsigned short us8;

static __device__ __forceinline__ float b2f(unsigned short u) {
  return __uint_as_float(((unsigned)u) << 16);
}
static __device__ __forceinline__ unsigned short f2b(float f) {
  __hip_bfloat16 h = __float2bfloat16(f);
  return __builtin_bit_cast(unsigned short, h);
}

// ---------------- CSR build ----------------

__global__ __launch_bounds__(256) void k_zero(int* __restrict__ p, int n) {
  int i = blockIdx.x * 256 + threadIdx.x;
  if (i < n) p[i] = 0;
}

__global__ __launch_bounds__(256) void k_hist(const int* __restrict__ dst, int E, int* __restrict__ deg) {
  int e0 = blockIdx.x * 2048 + threadIdx.x;
#pragma unroll
  for (int i = 0; i < 8; ++i) {
    int e = e0 + i * 256;
    if (e < E) atomicAdd(&deg[dst[e]], 1);
  }
}

// one block per 256-node chunk: LDS tree-reduce (was 391 threads x 256 serial loads)
__global__ __launch_bounds__(256) void k_scan_a(const int* __restrict__ deg, int N,
                                                int* __restrict__ csum) {
  __shared__ int buf[256];
  int c = blockIdx.x, t = threadIdx.x;
  int i = c * 256 + t;
  buf[t] = (i < N) ? deg[i] : 0;
  __syncthreads();
  for (int off = 128; off > 0; off >>= 1) {
    if (t < off) buf[t] += buf[t + off];
    __syncthreads();
  }
  if (t == 0) csum[c] = buf[0];
}

__global__ __launch_bounds__(512) void k_scan_b(const int* __restrict__ csum, int NCH,
                                                int* __restrict__ coff) {
  __shared__ int buf[512];
  int t = threadIdx.x;
  int v = (t < NCH) ? csum[t] : 0;
  buf[t] = v;
  __syncthreads();
  for (int off = 1; off < 512; off <<= 1) {
    int x = (t >= off) ? buf[t - off] : 0;
    __syncthreads();
    buf[t] += x;
    __syncthreads();
  }
  if (t < NCH) coff[t] = buf[t] - v;
}

__global__ __launch_bounds__(256) void k_scan_c(const int* __restrict__ deg, const int* __restrict__ coff,
                                                int N, int E, int* __restrict__ rowptr,
                                                int* __restrict__ wp) {
  __shared__ int buf[256];
  int c = blockIdx.x, t = threadIdx.x;
  int i = c * 256 + t;
  int v = (i < N) ? deg[i] : 0;
  buf[t] = v;
  __syncthreads();
  for (int off = 1; off < 256; off <<= 1) {
    int x = (t >= off) ? buf[t - off] : 0;
    __syncthreads();
    buf[t] += x;
    __syncthreads();
  }
  if (i < N) {
    int rp = coff[c] + buf[t] - v;
    rowptr[i] = rp;
    wp[i] = rp;
  }
  if (c == 0 && t == 0) rowptr[N] = E;
}

// 8 independent atomic+scatter chains per thread (R4 win)
__global__ __launch_bounds__(256) void k_fill(const int* __restrict__ src, const int* __restrict__ dst,
                                              int E, int* __restrict__ wp, int* __restrict__ colsrc) {
  int e0 = blockIdx.x * 2048 + threadIdx.x;
  int d[8], sv[8], p[8];
  bool ok[8];
#pragma unroll
  for (int i = 0; i < 8; ++i) {
    int e = e0 + i * 256;
    ok[i] = (e < E);
    if (ok[i]) { d[i] = dst[e]; sv[i] = src[e]; }
  }
#pragma unroll
  for (int i = 0; i < 8; ++i)
    if (ok[i]) p[i] = atomicAdd(&wp[d[i]], 1);
#pragma unroll
  for (int i = 0; i < 8; ++i)
    if (ok[i]) colsrc[p[i]] = sv[i];
}

// ---------------- weight pack: fp32 [k][n] -> bf16 [n][k_pos] ----------------
// n-dim IDENTITY (epilogue store address realizes the permutation).
// k-dim: position k_pos holds logical kk = L(k_pos) = 16*(k_pos&7)+(k_pos>>3).

#define PACK_FC   278528
#define PACK_TOT  284672

__global__ __launch_bounds__(256) void k_pack(const float* __restrict__ linW,
                                              const float* __restrict__ Wq, const float* __restrict__ Wk,
                                              const float* __restrict__ Wv, const float* __restrict__ Ws,
                                              const float* __restrict__ fcW,
                                              unsigned short* __restrict__ Wp) {
  int idx = blockIdx.x * 256 + threadIdx.x;
  float val;
  if (idx < 16384) {
    int n = idx >> 7, kk = idx & 127;               // n identity, k standard
    val = linW[kk * 128 + n];
  } else if (idx < PACK_FC) {
    int t = idx - 16384;
    int l = t >> 16, r = t & 65535;
    int n_pos = r >> 7, k_pos = r & 127;
    int which = n_pos >> 7;
    int nn = n_pos & 127;                           // n identity
    int kk = 16 * (k_pos & 7) + (k_pos >> 3);       // k = L(k_pos)
    const float* W = (which == 0) ? Wq : (which == 1) ? Wk : (which == 2) ? Wv : Ws;
    val = W[(size_t)l * 16384 + kk * 128 + nn];
  } else if (idx < PACK_TOT) {
    int t = idx - PACK_FC;
    int n = t >> 7, k_pos = t & 127;
    int kk = 16 * (k_pos & 7) + (k_pos >> 3);       // k = L(k_pos); n identity
    val = (n < ODIM) ? fcW[kk * ODIM + n] : 0.f;
  } else {
    return;
  }
  Wp[idx] = f2b(val);
}

// ---------------- GEMM lin: hb[N,128] = bf16( x @ linW + linb ), layout L ----

__global__ __launch_bounds__(256) void k_gemm_lin(const float* __restrict__ x,
                                                  const unsigned short* __restrict__ wl,
                                                  const float* __restrict__ bias,
                                                  unsigned short* __restrict__ hb, int N) {
  __shared__ unsigned short As[32 * LDSA];
  int t = threadIdx.x;
  int rowbase = blockIdx.x * 32;
#pragma unroll
  for (int i = 0; i < 2; ++i) {
    int c = t + i * 256;
    int r = c >> 4, c8 = c & 15;
    int gr = rowbase + r;
    if (gr >= N) gr = N - 1;
    const float4* xp = (const float4*)(x + (size_t)gr * 128 + c8 * 8);
    float4 u0 = xp[0], u1 = xp[1];
    us8 o;
    o[0] = f2b(u0.x); o[1] = f2b(u0.y); o[2] = f2b(u0.z); o[3] = f2b(u0.w);
    o[4] = f2b(u1.x); o[5] = f2b(u1.y); o[6] = f2b(u1.z); o[7] = f2b(u1.w);
    *(us8*)(As + r * LDSA + c8 * 8) = o;
  }
  __syncthreads();

  int lane = t & 63, w = t >> 6;
  int rh = (w & 1) * 16;
  int ch = (w >> 1) * 64;
  int lm = lane & 15, lq = lane >> 4;

  short8 a[4];
#pragma unroll
  for (int ks = 0; ks < 4; ++ks)
    a[ks] = *(const short8*)(As + (rh + lm) * LDSA + ks * 32 + lq * 8);

  f4v acc[4];
#pragma unroll
  for (int ct = 0; ct < 4; ++ct) acc[ct] = (f4v){0.f, 0.f, 0.f, 0.f};

#pragma unroll
  for (int ct = 0; ct < 4; ++ct) {
    const short8* bp = (const short8*)(wl + ((size_t)(ch + ct * 16 + lm)) * 128 + lq * 8);
    short8 b0 = bp[0], b1 = bp[4], b2 = bp[8], b3 = bp[12];
    acc[ct] = __builtin_amdgcn_mfma_f32_16x16x32_bf16(a[0], b0, acc[ct], 0, 0, 0);
    acc[ct] = __builtin_amdgcn_mfma_f32_16x16x32_bf16(a[1], b1, acc[ct], 0, 0, 0);
    acc[ct] = __builtin_amdgcn_mfma_f32_16x16x32_bf16(a[2], b2, acc[ct], 0, 0, 0);
    acc[ct] = __builtin_amdgcn_mfma_f32_16x16x32_bf16(a[3], b3, acc[ct], 0, 0, 0);
  }

  float bv[4];
#pragma unroll
  for (int ct = 0; ct < 4; ++ct) bv[ct] = bias[ch + ct * 16 + lm];

  // store B-row np=ch+ct*16+lm at position pi(np)=lm*8+(w>>1)*4+ct
#pragma unroll
  for (int r = 0; r < 4; ++r) {
    int row = rowbase + rh + lq * 4 + r;
    if (row < N) {
      us4 ov;
#pragma unroll
      for (int ct = 0; ct < 4; ++ct) ov[ct] = f2b(acc[ct][r] + bv[ct]);
      *(us4*)(hb + (size_t)row * 128 + lm * 8 + (w >> 1) * 4) = ov;
    }
  }
}

// ---------------- GEMM fused qkvs: wave w computes tensor w (32r x 128c) -------
// epilogue: q,v,s bf16 us8; k fp8 e4m3 (QK_SCALE folded) uint2.

__global__ __launch_bounds__(256, 3) void k_gemm_qkvs(const unsigned short* __restrict__ hb,
                                                      const unsigned short* __restrict__ wl,
                                                      const float* __restrict__ bq, const float* __restrict__ bk,
                                                      const float* __restrict__ bv, const float* __restrict__ bs,
                                                      unsigned short* __restrict__ q, unsigned char* __restrict__ k8,
                                                      unsigned short* __restrict__ v, unsigned short* __restrict__ s,
                                                      int N) {
  __shared__ unsigned short As[32 * LDSA];
  int t = threadIdx.x;
  int rowbase = blockIdx.x * 32;
#pragma unroll
  for (int i = 0; i < 2; ++i) {
    int c = t + i * 256;
    int r = c >> 4, c8 = c & 15;
    int gr = rowbase + r;
    if (gr >= N) gr = N - 1;
    *(us8*)(As + r * LDSA + c8 * 8) = *(const us8*)(hb + (size_t)gr * 128 + c8 * 8);
  }
  __syncthreads();

  int lane = t & 63, w = t >> 6;   // w: 0 q, 1 k, 2 v, 3 s
  int lm = lane & 15, lq = lane >> 4;

  short8 a[2][4];
#pragma unroll
  for (int rt = 0; rt < 2; ++rt)
#pragma unroll
    for (int ks = 0; ks < 4; ++ks)
      a[rt][ks] = *(const short8*)(As + (rt * 16 + lm) * LDSA + ks * 32 + lq * 8);

  f4v acc[2][8];
#pragma unroll
  for (int rt = 0; rt < 2; ++rt)
#pragma unroll
    for (int ct = 0; ct < 8; ++ct) acc[rt][ct] = (f4v){0.f, 0.f, 0.f, 0.f};

  const unsigned short* wb = wl + (size_t)w * 16384;
#pragma unroll
  for (int ct = 0; ct < 8; ++ct) {
    const short8* bp = (const short8*)(wb + (size_t)(ct * 16 + lm) * 128 + lq * 8);
    short8 b0 = bp[0], b1 = bp[4], b2 = bp[8], b3 = bp[12];
#pragma unroll
    for (int rt = 0; rt < 2; ++rt) {
      acc[rt][ct] = __builtin_amdgcn_mfma_f32_16x16x32_bf16(a[rt][0], b0, acc[rt][ct], 0, 0, 0);
      acc[rt][ct] = __builtin_amdgcn_mfma_f32_16x16x32_bf16(a[rt][1], b1, acc[rt][ct], 0, 0, 0);
      acc[rt][ct] = __builtin_amdgcn_mfma_f32_16x16x32_bf16(a[rt][2], b2, acc[rt][ct], 0, 0, 0);
      acc[rt][ct] = __builtin_amdgcn_mfma_f32_16x16x32_bf16(a[rt][3], b3, acc[rt][ct], 0, 0, 0);
    }
  }

  const float* bsel = (w == 0) ? bq : (w == 1) ? bk : (w == 2) ? bv : bs;
  float bias[8];
#pragma unroll
  for (int ct = 0; ct < 8; ++ct) bias[ct] = bsel[ct * 16 + lm];

#pragma unroll
  for (int rt = 0; rt < 2; ++rt) {
#pragma unroll
    for (int r = 0; r < 4; ++r) {
      int row = rowbase + rt * 16 + lq * 4 + r;
      if (row >= N) continue;
      float vals[8];
#pragma unroll
      for (int ct = 0; ct < 8; ++ct) vals[ct] = acc[rt][ct][r] + bias[ct];
      if (w == 1) {
        unsigned u0 = __builtin_amdgcn_cvt_pk_fp8_f32(vals[0] * QK_SCALE, vals[1] * QK_SCALE, 0, false);
        u0 = __builtin_amdgcn_cvt_pk_fp8_f32(vals[2] * QK_SCALE, vals[3] * QK_SCALE, u0, true);
        unsigned u1 = __builtin_amdgcn_cvt_pk_fp8_f32(vals[4] * QK_SCALE, vals[5] * QK_SCALE, 0, false);
        u1 = __builtin_amdgcn_cvt_pk_fp8_f32(vals[6] * QK_SCALE, vals[7] * QK_SCALE, u1, true);
        uint2 kw; kw.x = u0; kw.y = u1;
        *(uint2*)(k8 + (size_t)row * 128 + lm * 8) = kw;
      } else {
        us8 ov;
#pragma unroll
        for (int ct = 0; ct < 8; ++ct) ov[ct] = f2b(vals[ct]);
        unsigned short* outp = (w == 0) ? q : (w == 2) ? v : s;
        *(us8*)(outp + (size_t)row * 128 + lm * 8) = ov;
      }
    }
  }
}

// ---------------- attention: one wave/node, 4x16-lane slots, batch-2, fp8 k ----

__global__ __launch_bounds__(256) void k_attn8(const unsigned short* __restrict__ q,
                                               const unsigned char* __restrict__ kb8,
                                               const unsigned short* __restrict__ vb,
                                               const unsigned short* __restrict__ s,
                                               const int* __restrict__ rowptr, const int* __restrict__ colsrc,
                                               unsigned short* __restrict__ hb, int n, int do_elu) {
  int wid = blockIdx.x * 4 + (threadIdx.x >> 6);
  if (wid >= n) return;
  int lane = threadIdx.x & 63;
  int slot = lane >> 4;
  int lm = lane & 15;
  int d0 = lm * 8;

  us8 qu = *(const us8*)(q + (size_t)wid * 128 + d0);
  float qf[8];
#pragma unroll
  for (int i = 0; i < 8; ++i) qf[i] = b2f(qu[i]);

  int e0 = rowptr[wid], e1 = rowptr[wid + 1];
  int deg = e1 - e0;
  int cbase = deg >> 2, rem = deg & 3;
  int lo = e0 + slot * cbase + min(slot, rem);
  int hi = lo + cbase + (slot < rem ? 1 : 0);

  float M = -INFINITY, S = 0.f;
  float acc[8];
#pragma unroll
  for (int i = 0; i < 8; ++i) acc[i] = 0.f;

  int e = lo;
  for (; e + 1 < hi; e += 2) {
    int j0 = colsrc[e], j1 = colsrc[e + 1];
    uint2 kw0 = *(const uint2*)(kb8 + (size_t)j0 * 128 + d0);
    uint2 kw1 = *(const uint2*)(kb8 + (size_t)j1 * 128 + d0);
    us8 v0 = *(const us8*)(vb + (size_t)j0 * 128 + d0);
    us8 v1 = *(const us8*)(vb + (size_t)j1 * 128 + d0);
    f2v a01 = __builtin_amdgcn_cvt_pk_f32_fp8(kw0.x, false);
    f2v a23 = __builtin_amdgcn_cvt_pk_f32_fp8(kw0.x, true);
    f2v a45 = __builtin_amdgcn_cvt_pk_f32_fp8(kw0.y, false);
    f2v a67 = __builtin_amdgcn_cvt_pk_f32_fp8(kw0.y, true);
    f2v b01 = __builtin_amdgcn_cvt_pk_f32_fp8(kw1.x, false);
    f2v b23 = __builtin_amdgcn_cvt_pk_f32_fp8(kw1.x, true);
    f2v b45 = __builtin_amdgcn_cvt_pk_f32_fp8(kw1.y, false);
    f2v b67 = __builtin_amdgcn_cvt_pk_f32_fp8(kw1.y, true);
    float p0 = qf[0] * a01.x;
    p0 = fmaf(qf[1], a01.y, p0); p0 = fmaf(qf[2], a23.x, p0); p0 = fmaf(qf[3], a23.y, p0);
    p0 = fmaf(qf[4], a45.x, p0); p0 = fmaf(qf[5], a45.y, p0);
    p0 = fmaf(qf[6], a67.x, p0); p0 = fmaf(qf[7], a67.y, p0);
    float p1 = qf[0] * b01.x;
    p1 = fmaf(qf[1], b01.y, p1); p1 = fmaf(qf[2], b23.x, p1); p1 = fmaf(qf[3], b23.y, p1);
    p1 = fmaf(qf[4], b45.x, p1); p1 = fmaf(qf[5], b45.y, p1);
    p1 = fmaf(qf[6], b67.x, p1); p1 = fmaf(qf[7], b67.y, p1);
#pragma unroll
    for (int off = 1; off <= 8; off <<= 1) {
      p0 += __shfl_xor(p0, off, 64);
      p1 += __shfl_xor(p1, off, 64);
    }
    float l0 = p0, l1 = p1;  // QK_SCALE folded into k
    float newM = fmaxf(M, fmaxf(l0, l1));
    float f = __expf(M - newM);
    float w0 = __expf(l0 - newM), w1 = __expf(l1 - newM);
    S = S * f + w0 + w1;
#pragma unroll
    for (int i = 0; i < 8; ++i)
      acc[i] = fmaf(acc[i], f, fmaf(w0, b2f(v0[i]), w1 * b2f(v1[i])));
    M = newM;
  }
  if (e < hi) {
    int j0 = colsrc[e];
    uint2 kw0 = *(const uint2*)(kb8 + (size_t)j0 * 128 + d0);
    us8 v0 = *(const us8*)(vb + (size_t)j0 * 128 + d0);
    f2v a01 = __builtin_amdgcn_cvt_pk_f32_fp8(kw0.x, false);
    f2v a23 = __builtin_amdgcn_cvt_pk_f32_fp8(kw0.x, true);
    f2v a45 = __builtin_amdgcn_cvt_pk_f32_fp8(kw0.y, false);
    f2v a67 = __builtin_amdgcn_cvt_pk_f32_fp8(kw0.y, true);
    float p0 = qf[0] * a01.x;
    p0 = fmaf(qf[1], a01.y, p0); p0 = fmaf(qf[2], a23.x, p0); p0 = fmaf(qf[3], a23.y, p0);
    p0 = fmaf(qf[4], a45.x, p0); p0 = fmaf(qf[5], a45.y, p0);
    p0 = fmaf(qf[6], a67.x, p0); p0 = fmaf(qf[7], a67.y, p0);
#pragma unroll
    for (int off = 1; off <= 8; off <<= 1) p0 += __shfl_xor(p0, off, 64);
    float l0 = p0;
    float newM = fmaxf(M, l0);
    float f = __expf(M - newM);
    float w0 = __expf(l0 - newM);
    S = S * f + w0;
#pragma unroll
    for (int i = 0; i < 8; ++i) acc[i] = fmaf(acc[i], f, w0 * b2f(v0[i]));
    M = newM;
  }

  // merge 4 slots (xor 16, then xor 32), guarded for empty (-inf) states
#pragma unroll
  for (int off = 16; off <= 32; off <<= 1) {
    float Mo = __shfl_xor(M, off, 64);
    float So = __shfl_xor(S, off, 64);
    float bo[8];
#pragma unroll
    for (int i = 0; i < 8; ++i) bo[i] = __shfl_xor(acc[i], off, 64);
    float newM = fmaxf(M, Mo);
    float fs, fo;
    if (newM == -INFINITY) {
      fs = 0.f; fo = 0.f;
    } else {
      fs = __expf(M - newM);
      fo = __expf(Mo - newM);
    }
    S = S * fs + So * fo;
#pragma unroll
    for (int i = 0; i < 8; ++i) acc[i] = acc[i] * fs + bo[i] * fo;
    M = newM;
  }

  if (slot == 0) {
    float inv = (S > 0.f) ? 1.f / S : 0.f;
    us8 sk = *(const us8*)(s + (size_t)wid * 128 + d0);
    us8 ov;
#pragma unroll
    for (int i = 0; i < 8; ++i) {
      float x = acc[i] * inv + b2f(sk[i]);
      if (do_elu) x = (x > 0.f) ? x : (__expf(x) - 1.f);
      ov[i] = f2b(x);
    }
    *(us8*)(hb + (size_t)wid * 128 + d0) = ov;
  }
}

// ---------------- MFMA classifier + fused log_softmax ----------------

__global__ __launch_bounds__(256) void k_fc_mfma(const unsigned short* __restrict__ hb,
                                                 const unsigned short* __restrict__ fcp,
                                                 const float* __restrict__ fcb,
                                                 float* __restrict__ out, int N) {
  __shared__ unsigned short As[64 * LDSA];
  int t = threadIdx.x;
  int rowbase = blockIdx.x * 64;
#pragma unroll
  for (int i = 0; i < 4; ++i) {
    int c = t + i * 256;
    int r = c >> 4, c8 = c & 15;
    int gr = rowbase + r;
    if (gr >= N) gr = N - 1;
    us8 val = *(const us8*)(hb + (size_t)gr * 128 + c8 * 8);
    *(us8*)(As + r * LDSA + c8 * 8) = val;
  }
  __syncthreads();

  int lane = t & 63, w = t >> 6;
  int rh = w * 16;
  int lm = lane & 15, lq = lane >> 4;

  short8 a[4];
#pragma unroll
  for (int ks = 0; ks < 4; ++ks)
    a[ks] = *(const short8*)(As + (rh + lm) * LDSA + ks * 32 + lq * 8);

  f4v acc[3];
#pragma unroll
  for (int ct = 0; ct < 3; ++ct) acc[ct] = (f4v){0.f, 0.f, 0.f, 0.f};

#pragma unroll
  for (int ct = 0; ct < 3; ++ct) {
    const short8* bp = (const short8*)(fcp + ((size_t)(ct * 16 + lm)) * 128 + lq * 8);
    short8 b0 = bp[0], b1 = bp[4], b2 = bp[8], b3 = bp[12];
    acc[ct] = __builtin_amdgcn_mfma_f32_16x16x32_bf16(a[0], b0, acc[ct], 0, 0, 0);
    acc[ct] = __builtin_amdgcn_mfma_f32_16x16x32_bf16(a[1], b1, acc[ct], 0, 0, 0);
    acc[ct] = __builtin_amdgcn_mfma_f32_16x16x32_bf16(a[2], b2, acc[ct], 0, 0, 0);
    acc[ct] = __builtin_amdgcn_mfma_f32_16x16x32_bf16(a[3], b3, acc[ct], 0, 0, 0);
  }

  float bias[3];
#pragma unroll
  for (int ct = 0; ct < 3; ++ct) {
    int c = ct * 16 + lm;
    bias[ct] = (c < ODIM) ? fcb[c] : 0.f;
  }

#pragma unroll
  for (int r = 0; r < 4; ++r) {
    float v0 = acc[0][r] + bias[0];
    float v1 = acc[1][r] + bias[1];
    float v2 = (32 + lm < ODIM) ? (acc[2][r] + bias[2]) : -INFINITY;
    float m = fmaxf(fmaxf(v0, v1), v2);
#pragma unroll
    for (int off = 1; off <= 8; off <<= 1) m = fmaxf(m, __shfl_xor(m, off, 64));
    float sum = __expf(v0 - m) + __expf(v1 - m) + ((32 + lm < ODIM) ? __expf(v2 - m) : 0.f);
#pragma unroll
    for (int off = 1; off <= 8; off <<= 1) sum += __shfl_xor(sum, off, 64);
    float lse = m + logf(sum);
    int row = rowbase + rh + lq * 4 + r;
    if (row < N) {
      float* orow = out + (size_t)row * ODIM;
      orow[lm] = v0 - lse;
      orow[16 + lm] = v1 - lse;
      if (32 + lm < ODIM) orow[32 + lm] = v2 - lse;
    }
  }
}

// ---------------- host ----------------

extern "C" void kernel_launch(void* const* d_in, const int* in_sizes, int n_in,
                              void* d_out, int out_size, void* d_ws, size_t ws_size,
                              hipStream_t stream) {
  const float* x    = (const float*)d_in[0];
  const int*   ei   = (const int*)d_in[1];
  const float* linW = (const float*)d_in[2];
  const float* linb = (const float*)d_in[3];
  const float* Wq   = (const float*)d_in[4];
  const float* bq   = (const float*)d_in[5];
  const float* Wk   = (const float*)d_in[6];
  const float* bk   = (const float*)d_in[7];
  const float* Wv   = (const float*)d_in[8];
  const float* bv   = (const float*)d_in[9];
  const float* Wsk  = (const float*)d_in[10];
  const float* bsk  = (const float*)d_in[11];
  const float* fcW  = (const float*)d_in[12];
  const float* fcb  = (const float*)d_in[13];
  float* out = (float*)d_out;

  const int N = in_sizes[0] / HD;
  const int E = in_sizes[1] / 2;
  const int* srcv = ei;
  const int* dstv = ei + E;

  size_t off = 0;
  char* base = (char*)d_ws;
  auto carve = [&](size_t bytes) -> void* {
    void* p = base + off;
    off = (off + bytes + 255) & ~(size_t)255;
    return p;
  };
  unsigned short* Wp = (unsigned short*)carve((size_t)PACK_TOT * 2);
  unsigned short* hb = (unsigned short*)carve((size_t)N * HD * 2);
  unsigned short* qb = (unsigned short*)carve((size_t)N * HD * 2);
  unsigned char*  k8 = (unsigned char*)carve((size_t)N * HD);
  unsigned short* vbuf = (unsigned short*)carve((size_t)N * HD * 2);
  unsigned short* sbuf = (unsigned short*)carve((size_t)N * HD * 2);
  int* deg    = (int*)carve((size_t)N * 4);
  int* wp     = (int*)carve((size_t)N * 4);
  int* rowptr = (int*)carve((size_t)(N + 1) * 4);
  int* colsrc = (int*)carve((size_t)E * 4);
  int* csum   = (int*)carve(512 * 4);
  int* coff   = (int*)carve(512 * 4);
  (void)ws_size; (void)n_in; (void)out_size;

  const int NCH = (N + 255) / 256;
  dim3 blk(256);
  int nb = (N + 255) / 256;
  int gx = (N + 31) / 32;
  int wb = (N + 3) / 4;

  // CSR by dst
  k_zero<<<nb, blk, 0, stream>>>(deg, N);
  k_hist<<<(E + 2047) / 2048, blk, 0, stream>>>(dstv, E, deg);
  k_scan_a<<<NCH, blk, 0, stream>>>(deg, N, csum);
  k_scan_b<<<1, 512, 0, stream>>>(csum, NCH, coff);
  k_scan_c<<<NCH, blk, 0, stream>>>(deg, coff, N, E, rowptr, wp);
  k_fill<<<(E + 2047) / 2048, blk, 0, stream>>>(srcv, dstv, E, wp, colsrc);

  // weight pack (k-dim permuted to layout L, n-dim identity)
  k_pack<<<(PACK_TOT + 255) / 256, blk, 0, stream>>>(linW, Wq, Wk, Wv, Wsk, fcW, Wp);

  // input projection
  k_gemm_lin<<<gx, blk, 0, stream>>>(x, Wp, linb, hb, N);

  // layers
  for (int l = 0; l < 4; ++l) {
    const unsigned short* wl = Wp + 16384 + (size_t)l * 65536;
    k_gemm_qkvs<<<gx, blk, 0, stream>>>(hb, wl, bq + l * HD, bk + l * HD, bv + l * HD, bsk + l * HD,
                                        qb, k8, vbuf, sbuf, N);
    k_attn8<<<wb, blk, 0, stream>>>(qb, k8, vbuf, sbuf, rowptr, colsrc, hb, N, (l < 3) ? 1 : 0);
  }

  // classifier + fused log_softmax
  k_fc_mfma<<<(N + 63) / 64, blk, 0, stream>>>(hb, Wp + PACK_FC, fcb, out, N);
}